// Round 4
// baseline (468.018 us; speedup 1.0000x reference)
//
#include <hip/hip_runtime.h>
#include <stdint.h>

#define DEVI __device__ __forceinline__

typedef unsigned short ushort_t;
typedef __bf16 bf16x8 __attribute__((ext_vector_type(8)));
typedef float f32x4 __attribute__((ext_vector_type(4)));
typedef unsigned short ushort8 __attribute__((ext_vector_type(8)));

// ---- constants ----
#define BB 4
#define TT 2048
#define CC 1024
#define NH 16
#define HD 64
#define MM (BB*TT)          // 8192

DEVI ushort_t f2bf(float f) {
    union { float f; unsigned u; } v; v.f = f;
    return (ushort_t)((v.u + 0x7FFFu + ((v.u >> 16) & 1u)) >> 16);
}

// ---------------- fp32 -> bf16 bulk convert (8 elems/thread) ----------------
__global__ void cvt_f32_bf16(const float* __restrict__ in,
                             ushort_t* __restrict__ out) {
    int i = blockIdx.x * 256 + threadIdx.x;
    const float4* p = (const float4*)in + (size_t)i * 2;
    float4 a = p[0], b = p[1];
    ushort8 r;
    r[0] = f2bf(a.x); r[1] = f2bf(a.y); r[2] = f2bf(a.z); r[3] = f2bf(a.w);
    r[4] = f2bf(b.x); r[5] = f2bf(b.y); r[6] = f2bf(b.z); r[7] = f2bf(b.w);
    *(ushort8*)(out + (size_t)i * 8) = r;
}

// ------------- transpose fp32 -> bf16: in[R][Cc] -> out[Cc][R] -------------
__global__ void transpose_f2b(const float* __restrict__ in,
                              ushort_t* __restrict__ out, int R, int Cc) {
    __shared__ ushort_t tile[32][33];
    int bx = blockIdx.x * 32;   // col base in input
    int by = blockIdx.y * 32;   // row base in input
    int tx = threadIdx.x & 31, ty = threadIdx.x >> 5;  // ty 0..7
    #pragma unroll
    for (int i = 0; i < 4; i++) {
        int r = ty * 4 + i;
        tile[r][tx] = f2bf(in[(size_t)(by + r) * Cc + bx + tx]);
    }
    __syncthreads();
    #pragma unroll
    for (int i = 0; i < 4; i++) {
        int r = ty * 4 + i;
        out[(size_t)(bx + r) * R + by + tx] = tile[tx][r];
    }
}

// ---------------- rope table: tab[t*32+j] = (cos, sin) ----------------
__global__ void rope_table(float2* __restrict__ tab) {
    int i = blockIdx.x * 256 + threadIdx.x;   // 65536 total
    int t = i >> 5, j = i & 31;
    // theta = t * 10000^(-j/32) = t * exp2(-j * log2(10000)/32)
    float inv = exp2f((float)j * -0.41524101186092029f);
    float theta = (float)t * inv;
    float s, c;
    sincosf(theta, &s, &c);
    tab[i] = make_float2(c, s);
}

// ---------------- GEMM: C = A * Bt^T  (A,Bt bf16) ----------------
// MODE 1: A=[M][Kd] row-major; qkv epilogue: rope q,k; scatter to [B*NH][T][HD]
// MODE 2: A is head-major [(b*16+h)*2048+t][64] (logical [M][Kd], m=(b,t),
//         k=(h,kd)); fp32 store to CoutF[M][N]
template <int MODE>
__global__ __launch_bounds__(256, 2) void gemm_bt(
    const ushort_t* __restrict__ A, const ushort_t* __restrict__ Bt,
    float* __restrict__ CoutF,
    ushort_t* __restrict__ Qb, ushort_t* __restrict__ Kb, ushort_t* __restrict__ Vb,
    const float2* __restrict__ rope, int M, int N, int Kd) {
    __shared__ __attribute__((aligned(16))) ushort_t As[128 * 32];
    __shared__ __attribute__((aligned(16))) ushort_t Bs[128 * 32];

    const int tid = threadIdx.x;
    const int w = tid >> 6, l = tid & 63;
    const int lane15 = l & 15, quad = l >> 4;
    const int wm = (w >> 1) * 64, wn = (w & 1) * 64;
    const int bm = blockIdx.y, bn = blockIdx.x;

    f32x4 acc[4][4];
    #pragma unroll
    for (int i = 0; i < 4; i++)
        #pragma unroll
        for (int j = 0; j < 4; j++)
            acc[i][j] = f32x4{0.f, 0.f, 0.f, 0.f};

    const int c0 = w * 2, c1 = w * 2 + 1;
    const int lr = l >> 2, lc = (l & 3) * 8;
    const int rowA0 = bm * 128 + c0 * 16 + lr;
    const int rowA1 = bm * 128 + c1 * 16 + lr;
    const ushort_t *gA0, *gA1;
    if (MODE == 2) {
        gA0 = A + ((size_t)(rowA0 >> 11) * 32768 + (rowA0 & (TT - 1))) * HD + lc;
        gA1 = A + ((size_t)(rowA1 >> 11) * 32768 + (rowA1 & (TT - 1))) * HD + lc;
    } else {
        gA0 = A + (size_t)rowA0 * Kd + lc;
        gA1 = A + (size_t)rowA1 * Kd + lc;
    }
    const ushort_t* gB0 = Bt + (size_t)(bn * 128 + c0 * 16 + lr) * Kd + lc;
    const ushort_t* gB1 = Bt + (size_t)(bn * 128 + c1 * 16 + lr) * Kd + lc;

    for (int k0 = 0; k0 < Kd; k0 += 32) {
        // head-major A: k=(h,kd): offset = h*2048*64 + kd = (k0>>6)*131072 + (k0&63)
        size_t offA = (MODE == 2) ? ((size_t)(k0 >> 6) * 131072 + (size_t)(k0 & 63))
                                  : (size_t)k0;
        ushort8 a0 = *(const ushort8*)(gA0 + offA);
        ushort8 a1 = *(const ushort8*)(gA1 + offA);
        ushort8 b0 = *(const ushort8*)(gB0 + k0);
        ushort8 b1 = *(const ushort8*)(gB1 + k0);
        __syncthreads();   // previous iteration's LDS readers are done
        *(ushort8*)&As[c0 * 512 + l * 8] = a0;   // byte ofs = c0*1024 + l*16
        *(ushort8*)&As[c1 * 512 + l * 8] = a1;
        *(ushort8*)&Bs[c0 * 512 + l * 8] = b0;
        *(ushort8*)&Bs[c1 * 512 + l * 8] = b1;
        __syncthreads();

        bf16x8 af[4], bf[4];
        #pragma unroll
        for (int t = 0; t < 4; t++) {
            af[t] = *(const bf16x8*)&As[(wm + t * 16 + lane15) * 32 + quad * 8];
            bf[t] = *(const bf16x8*)&Bs[(wn + t * 16 + lane15) * 32 + quad * 8];
        }
        #pragma unroll
        for (int tm = 0; tm < 4; tm++)
            #pragma unroll
            for (int tn = 0; tn < 4; tn++)
                acc[tm][tn] = __builtin_amdgcn_mfma_f32_16x16x32_bf16(
                    af[tm], bf[tn], acc[tm][tn], 0, 0, 0);
    }

    if (MODE == 2) {
        #pragma unroll
        for (int tm = 0; tm < 4; tm++) {
            int row0 = bm * 128 + wm + tm * 16 + quad * 4;
            #pragma unroll
            for (int r = 0; r < 4; r++) {
                size_t rb = (size_t)(row0 + r) * N + bn * 128 + wn;
                #pragma unroll
                for (int tn = 0; tn < 4; tn++)
                    CoutF[rb + tn * 16 + lane15] = acc[tm][tn][r];
            }
        }
    } else {
        const int colbase = bn * 128 + wn;          // multiple of 64
        const int seg = colbase >> 10;              // 0=q 1=k 2=v
        const int h = (colbase & 1023) >> 6;        // head (whole wave same head)
        #pragma unroll
        for (int tm = 0; tm < 4; tm++) {
            int row0 = bm * 128 + wm + tm * 16 + quad * 4;
            #pragma unroll
            for (int r = 0; r < 4; r++) {
                int row = row0 + r;
                int b = row >> 11, t = row & (TT - 1);
                size_t ob = ((size_t)(b * NH + h) * TT + t) * HD;
                if (seg == 2) {
                    #pragma unroll
                    for (int tn = 0; tn < 4; tn++)
                        Vb[ob + tn * 16 + lane15] = f2bf(acc[tm][tn][r]);
                } else {
                    ushort_t* dst = (seg == 0) ? Qb : Kb;
                    #pragma unroll
                    for (int tn = 0; tn < 2; tn++) {
                        int j = tn * 16 + lane15;       // 0..31
                        float2 cs = rope[t * 32 + j];
                        float x1 = acc[tm][tn][r];      // d = j
                        float x2 = acc[tm][tn + 2][r];  // d = j+32
                        dst[ob + j]      = f2bf(x1 * cs.x - x2 * cs.y);
                        dst[ob + 32 + j] = f2bf(x2 * cs.x + x1 * cs.y);
                    }
                }
            }
        }
    }
}

// ---------------- flash attention (causal), O written in place over Q ------
// grid: (T/64, B*NH); block 256. wave w owns q rows q0+w*16 .. +15.
// Each Q row is read exactly once (by its owning wave) before that wave
// writes O to the same rows; no other block/wave touches the region -> safe.
__global__ __launch_bounds__(256, 2) void attn_kernel(
    ushort_t* __restrict__ Qb, const ushort_t* __restrict__ Kb,
    const ushort_t* __restrict__ Vb) {
    __shared__ __attribute__((aligned(16))) ushort_t Ks[64 * 72];
    __shared__ __attribute__((aligned(16))) ushort_t Vt[64 * 72];
    __shared__ __attribute__((aligned(16))) ushort_t Ps[4][16 * 72];

    const int tid = threadIdx.x;
    const int w = tid >> 6, l = tid & 63;
    const int lane15 = l & 15, quad = l >> 4;
    const int qt = blockIdx.x, bh = blockIdx.y;
    const int q0 = qt * 64;
    const size_t base = (size_t)bh * (TT * HD);

    // Q fragments (A-layout), held for the whole kernel
    bf16x8 qf[2];
    {
        const ushort_t* qp = Qb + base + (size_t)(q0 + w * 16 + lane15) * HD + quad * 8;
        qf[0] = *(const bf16x8*)qp;
        qf[1] = *(const bf16x8*)(qp + 32);
    }

    f32x4 o[4];
    #pragma unroll
    for (int nt = 0; nt < 4; nt++) o[nt] = f32x4{0.f, 0.f, 0.f, 0.f};
    float mrow[4] = {-INFINITY, -INFINITY, -INFINITY, -INFINITY};
    float lrow[4] = {0.f, 0.f, 0.f, 0.f};
    const float SC = 0.125f * 1.4426950408889634f;  // scale * log2(e)

    const int sr = tid >> 2;         // staging row 0..63
    const int sd = (tid & 3) * 16;   // staging col 0/16/32/48

    for (int kt = 0; kt <= qt; kt++) {
        __syncthreads();
        {   // stage K row-major [64][72], V transposed [64][72]
            const ushort_t* kg = Kb + base + (size_t)(kt * 64 + sr) * HD + sd;
            ushort8 ka = *(const ushort8*)kg;
            ushort8 kb2 = *(const ushort8*)(kg + 8);
            *(ushort8*)&Ks[sr * 72 + sd] = ka;
            *(ushort8*)&Ks[sr * 72 + sd + 8] = kb2;
            const ushort_t* vg = Vb + base + (size_t)(kt * 64 + sr) * HD + sd;
            ushort8 va = *(const ushort8*)vg;
            ushort8 vb2 = *(const ushort8*)(vg + 8);
            #pragma unroll
            for (int j = 0; j < 8; j++) Vt[(sd + j) * 72 + sr] = va[j];
            #pragma unroll
            for (int j = 0; j < 8; j++) Vt[(sd + 8 + j) * 72 + sr] = vb2[j];
        }
        __syncthreads();

        // S = Q K^T  (C-layout: row=quad*4+r, col=nt*16+lane15)
        f32x4 s[4];
        #pragma unroll
        for (int nt = 0; nt < 4; nt++) {
            bf16x8 k0 = *(const bf16x8*)&Ks[(nt * 16 + lane15) * 72 + quad * 8];
            bf16x8 k1 = *(const bf16x8*)&Ks[(nt * 16 + lane15) * 72 + 32 + quad * 8];
            f32x4 z = f32x4{0.f, 0.f, 0.f, 0.f};
            z = __builtin_amdgcn_mfma_f32_16x16x32_bf16(qf[0], k0, z, 0, 0, 0);
            s[nt] = __builtin_amdgcn_mfma_f32_16x16x32_bf16(qf[1], k1, z, 0, 0, 0);
        }

        const bool diag = (kt == qt);
        #pragma unroll
        for (int nt = 0; nt < 4; nt++)
            #pragma unroll
            for (int r = 0; r < 4; r++) {
                float sv = s[nt][r] * SC;
                if (diag && (kt * 64 + nt * 16 + lane15 > q0 + w * 16 + quad * 4 + r))
                    sv = -1e9f;
                s[nt][r] = sv;
            }

        // row max (across nt, then across the 16 lanes sharing a quad)
        float mt[4];
        #pragma unroll
        for (int r = 0; r < 4; r++)
            mt[r] = fmaxf(fmaxf(s[0][r], s[1][r]), fmaxf(s[2][r], s[3][r]));
        #pragma unroll
        for (int off = 1; off < 16; off <<= 1)
            #pragma unroll
            for (int r = 0; r < 4; r++)
                mt[r] = fmaxf(mt[r], __shfl_xor(mt[r], off, 64));

        float alpha[4];
        #pragma unroll
        for (int r = 0; r < 4; r++) {
            float mn = fmaxf(mrow[r], mt[r]);
            alpha[r] = exp2f(mrow[r] - mn);
            mrow[r] = mn;
        }
        #pragma unroll
        for (int nt = 0; nt < 4; nt++)
            #pragma unroll
            for (int r = 0; r < 4; r++)
                s[nt][r] = exp2f(s[nt][r] - mrow[r]);

        float rs[4];
        #pragma unroll
        for (int r = 0; r < 4; r++)
            rs[r] = (s[0][r] + s[1][r]) + (s[2][r] + s[3][r]);
        #pragma unroll
        for (int off = 1; off < 16; off <<= 1)
            #pragma unroll
            for (int r = 0; r < 4; r++)
                rs[r] += __shfl_xor(rs[r], off, 64);
        #pragma unroll
        for (int r = 0; r < 4; r++)
            lrow[r] = lrow[r] * alpha[r] + rs[r];

        #pragma unroll
        for (int nt = 0; nt < 4; nt++)
            #pragma unroll
            for (int r = 0; r < 4; r++)
                o[nt][r] *= alpha[r];

        // P: C-layout -> LDS (per-wave region) -> A-layout read.
        #pragma unroll
        for (int nt = 0; nt < 4; nt++)
            #pragma unroll
            for (int r = 0; r < 4; r++)
                Ps[w][(quad * 4 + r) * 72 + nt * 16 + lane15] = f2bf(s[nt][r]);
        __syncthreads();   // uniform trip count across the block -> legal

        #pragma unroll
        for (int ch = 0; ch < 2; ch++) {
            bf16x8 pa = *(const bf16x8*)&Ps[w][lane15 * 72 + ch * 32 + quad * 8];
            #pragma unroll
            for (int nt = 0; nt < 4; nt++) {
                bf16x8 vf = *(const bf16x8*)&Vt[(nt * 16 + lane15) * 72 + ch * 32 + quad * 8];
                o[nt] = __builtin_amdgcn_mfma_f32_16x16x32_bf16(pa, vf, o[nt], 0, 0, 0);
            }
        }
    }

    // write O in place over this tile's Q rows (head-major layout)
    #pragma unroll
    for (int r = 0; r < 4; r++) {
        float inv = 1.0f / lrow[r];
        size_t rb = base + (size_t)(q0 + w * 16 + quad * 4 + r) * HD;
        #pragma unroll
        for (int nt = 0; nt < 4; nt++)
            Qb[rb + nt * 16 + lane15] = f2bf(o[nt][r] * inv);
    }
}

// ---------------- launch ----------------
extern "C" void kernel_launch(void* const* d_in, const int* in_sizes, int n_in,
                              void* d_out, int out_size, void* d_ws, size_t ws_size,
                              hipStream_t stream) {
    // Inputs are FLOAT32 per the reference; output FLOAT32.
    const float* x    = (const float*)d_in[0];   // [8192][1024]
    const float* wqkv = (const float*)d_in[1];   // [1024][3072]
    const float* wout = (const float*)d_in[2];   // [1024][1024]
    float* out = (float*)d_out;

    // ws layout (72.5 MiB total):
    char* ws = (char*)d_ws;
    ushort_t* WqkvT = (ushort_t*)(ws);                        // [3072][1024] bf16, 6291456 B
    ushort_t* WoutT = (ushort_t*)(ws + 6291456);              // [1024][1024] bf16, 2097152 B
    float2*   rope  = (float2*)  (ws + 8388608);              // [2048*32] fp32x2, 524288 B
    ushort_t* Xb    = (ushort_t*)(ws + 8912896);              // [8192][1024] bf16, 16 MiB
    ushort_t* Qb    = (ushort_t*)(ws + 8912896 + 16777216);   // [64][2048][64] bf16
    ushort_t* Kb    = (ushort_t*)(ws + 8912896 + 2 * 16777216);
    ushort_t* Vb    = (ushort_t*)(ws + 8912896 + 3 * 16777216);
    // total = 8912896 + 4*16777216 = 76021760 B

    cvt_f32_bf16<<<dim3(MM * CC / (256 * 8)), 256, 0, stream>>>(x, Xb);
    transpose_f2b<<<dim3(3 * CC / 32, CC / 32), 256, 0, stream>>>(wqkv, WqkvT, CC, 3 * CC);
    transpose_f2b<<<dim3(CC / 32, CC / 32), 256, 0, stream>>>(wout, WoutT, CC, CC);
    rope_table<<<dim3(256), 256, 0, stream>>>(rope);

    gemm_bt<1><<<dim3(3 * CC / 128, MM / 128), 256, 0, stream>>>(
        Xb, WqkvT, nullptr, Qb, Kb, Vb, rope, MM, 3 * CC, CC);

    attn_kernel<<<dim3(TT / 64, BB * NH), 256, 0, stream>>>(Qb, Kb, Vb);

    // final GEMM reads O from the head-major Qb buffer (MODE 2 addressing)
    gemm_bt<2><<<dim3(CC / 128, MM / 128), 256, 0, stream>>>(
        Qb, WoutT, out, nullptr, nullptr, nullptr, nullptr, MM, CC, CC);
}

// Round 5
// 435.380 us; speedup vs baseline: 1.0750x; 1.0750x over previous
//
#include <hip/hip_runtime.h>
#include <stdint.h>

#define DEVI __device__ __forceinline__

typedef unsigned short ushort_t;
typedef __bf16 bf16x8 __attribute__((ext_vector_type(8)));
typedef float f32x4 __attribute__((ext_vector_type(4)));
typedef unsigned short ushort8 __attribute__((ext_vector_type(8)));

// ---- constants ----
#define BB 4
#define TT 2048
#define CC 1024
#define NH 16
#define HD 64
#define MM (BB*TT)          // 8192

DEVI ushort_t f2bf(float f) {
    union { float f; unsigned u; } v; v.f = f;
    return (ushort_t)((v.u + 0x7FFFu + ((v.u >> 16) & 1u)) >> 16);
}

typedef const __attribute__((address_space(1))) unsigned int guint_t;
typedef __attribute__((address_space(3))) unsigned int luint_t;

// async global->LDS, 16B/lane; lds dest is wave-uniform base + lane*16
DEVI void gl2lds16(const void* g, void* lds) {
    __builtin_amdgcn_global_load_lds((guint_t*)(uintptr_t)g,
                                     (luint_t*)(unsigned int)(uintptr_t)lds,
                                     16, 0, 0);
}

// ---------------- fp32 -> bf16 bulk convert (8 elems/thread) ----------------
__global__ void cvt_f32_bf16(const float* __restrict__ in,
                             ushort_t* __restrict__ out) {
    int i = blockIdx.x * 256 + threadIdx.x;
    const float4* p = (const float4*)in + (size_t)i * 2;
    float4 a = p[0], b = p[1];
    ushort8 r;
    r[0] = f2bf(a.x); r[1] = f2bf(a.y); r[2] = f2bf(a.z); r[3] = f2bf(a.w);
    r[4] = f2bf(b.x); r[5] = f2bf(b.y); r[6] = f2bf(b.z); r[7] = f2bf(b.w);
    *(ushort8*)(out + (size_t)i * 8) = r;
}

// ------------- transpose fp32 -> bf16: in[R][Cc] -> out[Cc][R] -------------
__global__ void transpose_f2b(const float* __restrict__ in,
                              ushort_t* __restrict__ out, int R, int Cc) {
    __shared__ ushort_t tile[32][33];
    int bx = blockIdx.x * 32;
    int by = blockIdx.y * 32;
    int tx = threadIdx.x & 31, ty = threadIdx.x >> 5;
    #pragma unroll
    for (int i = 0; i < 4; i++) {
        int r = ty * 4 + i;
        tile[r][tx] = f2bf(in[(size_t)(by + r) * Cc + bx + tx]);
    }
    __syncthreads();
    #pragma unroll
    for (int i = 0; i < 4; i++) {
        int r = ty * 4 + i;
        out[(size_t)(bx + r) * R + by + tx] = tile[tx][r];
    }
}

// ---------------- rope table: tab[t*32+j] = (cos, sin) ----------------
__global__ void rope_table(float2* __restrict__ tab) {
    int i = blockIdx.x * 256 + threadIdx.x;   // 65536 total
    int t = i >> 5, j = i & 31;
    float inv = exp2f((float)j * -0.41524101186092029f);
    float theta = (float)t * inv;
    float s, c;
    sincosf(theta, &s, &c);
    tab[i] = make_float2(c, s);
}

// ------- V transpose: Vb[bh][t][d] -> VbT[bh][d][t], 64x64 tiles -------
__global__ void vtrans(const ushort_t* __restrict__ Vb,
                       ushort_t* __restrict__ VbT) {
    __shared__ ushort_t tile[64 * 72];
    const int bh = blockIdx.y;
    const int t0 = blockIdx.x * 64;
    const int tid = threadIdx.x;
    const int r = tid >> 2, c = (tid & 3) * 16;
    const size_t base = (size_t)bh * (TT * HD);
    const ushort_t* g = Vb + base + (size_t)(t0 + r) * HD + c;
    *(ushort8*)&tile[r * 72 + c]     = *(const ushort8*)g;
    *(ushort8*)&tile[r * 72 + c + 8] = *(const ushort8*)(g + 8);
    __syncthreads();
    ushort8 a, b;
    #pragma unroll
    for (int j = 0; j < 8; j++) a[j] = tile[(c + j) * 72 + r];
    #pragma unroll
    for (int j = 0; j < 8; j++) b[j] = tile[(c + 8 + j) * 72 + r];
    ushort_t* o = VbT + base + (size_t)r * TT + t0 + c;
    *(ushort8*)o = a;
    *(ushort8*)(o + 8) = b;
}

// ---------------- GEMM: C = A * Bt^T  (A,Bt bf16), m97 structure ----------
// MODE 1: A=[M][Kd] row-major; qkv epilogue: rope q,k; scatter to [B*NH][T][HD]
// MODE 2: A head-major [(b*16+h)*2048+t][64]; fp32 store to CoutF[M][N]
template <int MODE>
__global__ __launch_bounds__(256, 2) void gemm_bt(
    const ushort_t* __restrict__ A, const ushort_t* __restrict__ Bt,
    float* __restrict__ CoutF,
    ushort_t* __restrict__ Qb, ushort_t* __restrict__ Kb, ushort_t* __restrict__ Vb,
    const float2* __restrict__ rope, int M, int N, int Kd) {
    __shared__ __attribute__((aligned(16))) ushort_t As[128 * 32];
    __shared__ __attribute__((aligned(16))) ushort_t Bs[128 * 32];

    const int tid = threadIdx.x;
    const int w = tid >> 6, l = tid & 63;
    const int lane15 = l & 15, quad = l >> 4;
    const int wm = (w >> 1) * 64, wn = (w & 1) * 64;
    const int bm = blockIdx.y, bn = blockIdx.x;

    f32x4 acc[4][4];
    #pragma unroll
    for (int i = 0; i < 4; i++)
        #pragma unroll
        for (int j = 0; j < 4; j++)
            acc[i][j] = f32x4{0.f, 0.f, 0.f, 0.f};

    const int c0 = w * 2, c1 = w * 2 + 1;
    const int lr = l >> 2, lc = (l & 3) * 8;
    const int rowA0 = bm * 128 + c0 * 16 + lr;
    const int rowA1 = bm * 128 + c1 * 16 + lr;
    const ushort_t *gA0, *gA1;
    if (MODE == 2) {
        gA0 = A + ((size_t)(rowA0 >> 11) * 32768 + (rowA0 & (TT - 1))) * HD + lc;
        gA1 = A + ((size_t)(rowA1 >> 11) * 32768 + (rowA1 & (TT - 1))) * HD + lc;
    } else {
        gA0 = A + (size_t)rowA0 * Kd + lc;
        gA1 = A + (size_t)rowA1 * Kd + lc;
    }
    const ushort_t* gB0 = Bt + (size_t)(bn * 128 + c0 * 16 + lr) * Kd + lc;
    const ushort_t* gB1 = Bt + (size_t)(bn * 128 + c1 * 16 + lr) * Kd + lc;

    for (int k0 = 0; k0 < Kd; k0 += 32) {
        size_t offA = (MODE == 2) ? ((size_t)(k0 >> 6) * 131072 + (size_t)(k0 & 63))
                                  : (size_t)k0;
        __syncthreads();   // prior iter's LDS readers done
        gl2lds16(gA0 + offA, &As[c0 * 512]);
        gl2lds16(gA1 + offA, &As[c1 * 512]);
        gl2lds16(gB0 + k0,  &Bs[c0 * 512]);
        gl2lds16(gB1 + k0,  &Bs[c1 * 512]);
        __syncthreads();   // drains vmcnt -> staged data visible

        bf16x8 af[4], bf[4];
        #pragma unroll
        for (int t = 0; t < 4; t++) {
            af[t] = *(const bf16x8*)&As[(wm + t * 16 + lane15) * 32 + quad * 8];
            bf[t] = *(const bf16x8*)&Bs[(wn + t * 16 + lane15) * 32 + quad * 8];
        }
        #pragma unroll
        for (int tm = 0; tm < 4; tm++)
            #pragma unroll
            for (int tn = 0; tn < 4; tn++)
                acc[tm][tn] = __builtin_amdgcn_mfma_f32_16x16x32_bf16(
                    af[tm], bf[tn], acc[tm][tn], 0, 0, 0);
    }

    if (MODE == 2) {
        #pragma unroll
        for (int tm = 0; tm < 4; tm++) {
            int row0 = bm * 128 + wm + tm * 16 + quad * 4;
            #pragma unroll
            for (int r = 0; r < 4; r++) {
                size_t rb = (size_t)(row0 + r) * N + bn * 128 + wn;
                #pragma unroll
                for (int tn = 0; tn < 4; tn++)
                    CoutF[rb + tn * 16 + lane15] = acc[tm][tn][r];
            }
        }
    } else {
        const int colbase = bn * 128 + wn;          // multiple of 64
        const int seg = colbase >> 10;              // 0=q 1=k 2=v
        const int h = (colbase & 1023) >> 6;        // head
        #pragma unroll
        for (int tm = 0; tm < 4; tm++) {
            int row0 = bm * 128 + wm + tm * 16 + quad * 4;
            #pragma unroll
            for (int r = 0; r < 4; r++) {
                int row = row0 + r;
                int b = row >> 11, t = row & (TT - 1);
                size_t ob = ((size_t)(b * NH + h) * TT + t) * HD;
                if (seg == 2) {
                    #pragma unroll
                    for (int tn = 0; tn < 4; tn++)
                        Vb[ob + tn * 16 + lane15] = f2bf(acc[tm][tn][r]);
                } else {
                    ushort_t* dst = (seg == 0) ? Qb : Kb;
                    #pragma unroll
                    for (int tn = 0; tn < 2; tn++) {
                        int j = tn * 16 + lane15;       // 0..31
                        float2 cs = rope[t * 32 + j];
                        float x1 = acc[tm][tn][r];      // d = j
                        float x2 = acc[tm][tn + 2][r];  // d = j+32
                        dst[ob + j]      = f2bf(x1 * cs.x - x2 * cs.y);
                        dst[ob + 32 + j] = f2bf(x2 * cs.x + x1 * cs.y);
                    }
                }
            }
        }
    }
}

// ---------------- flash attention (causal), O in place over Q --------------
// grid: (T/128 heavy-first, B*NH); block 256. wave w owns 32 q rows
// (2 m-frags). K-tiles of 64, K/V staged double-pipelined; V from VbT.
__global__ __launch_bounds__(256, 2) void attn_kernel(
    ushort_t* __restrict__ Qb, const ushort_t* __restrict__ Kb,
    const ushort_t* __restrict__ VbT) {
    __shared__ __attribute__((aligned(16))) ushort_t Ks[64 * 72];
    __shared__ __attribute__((aligned(16))) ushort_t Vt[64 * 72];
    __shared__ __attribute__((aligned(16))) ushort_t Ps[4][32 * 72];

    const int tid = threadIdx.x;
    const int w = tid >> 6, l = tid & 63;
    const int lane15 = l & 15, quad = l >> 4;
    const int qt = (int)gridDim.x - 1 - (int)blockIdx.x;   // heavy blocks first
    const int bh = blockIdx.y;
    const int q0 = qt * 128;
    const int rbase = q0 + w * 32;
    const size_t base = (size_t)bh * (TT * HD);

    // Q fragments (A-layout), 2 m-frags x 2 k-chunks
    bf16x8 qf[2][2];
    #pragma unroll
    for (int mi = 0; mi < 2; mi++) {
        const ushort_t* qp = Qb + base + (size_t)(rbase + mi * 16 + lane15) * HD + quad * 8;
        qf[mi][0] = *(const bf16x8*)qp;
        qf[mi][1] = *(const bf16x8*)(qp + 32);
    }

    f32x4 o[2][4];
    float mrow[2][4], lrow[2][4];
    #pragma unroll
    for (int mi = 0; mi < 2; mi++)
        #pragma unroll
        for (int nt = 0; nt < 4; nt++) o[mi][nt] = f32x4{0.f, 0.f, 0.f, 0.f};
    #pragma unroll
    for (int mi = 0; mi < 2; mi++)
        #pragma unroll
        for (int r = 0; r < 4; r++) { mrow[mi][r] = -INFINITY; lrow[mi][r] = 0.f; }

    const float SC = 0.125f * 1.4426950408889634f;  // scale * log2(e)

    const int sr = tid >> 2;         // staging row 0..63
    const int sd = (tid & 3) * 16;   // staging col 0/16/32/48
    const int ktmax = (q0 + 127) >> 6;

    const ushort_t* kg = Kb  + base + (size_t)sr * HD + sd;   // + kt*64*HD
    const ushort_t* vg = VbT + base + (size_t)sr * TT + sd;   // + kt*64

    ushort8 kr0 = *(const ushort8*)kg, kr1 = *(const ushort8*)(kg + 8);
    ushort8 vr0 = *(const ushort8*)vg, vr1 = *(const ushort8*)(vg + 8);

    for (int kt = 0; kt <= ktmax; kt++) {
        __syncthreads();   // prior iter's LDS readers done
        *(ushort8*)&Ks[sr * 72 + sd]     = kr0;
        *(ushort8*)&Ks[sr * 72 + sd + 8] = kr1;
        *(ushort8*)&Vt[sr * 72 + sd]     = vr0;
        *(ushort8*)&Vt[sr * 72 + sd + 8] = vr1;
        __syncthreads();
        if (kt < ktmax) {   // prefetch next tile; overlaps with compute below
            const ushort_t* kg2 = kg + (size_t)(kt + 1) * 64 * HD;
            const ushort_t* vg2 = vg + (size_t)(kt + 1) * 64;
            kr0 = *(const ushort8*)kg2; kr1 = *(const ushort8*)(kg2 + 8);
            vr0 = *(const ushort8*)vg2; vr1 = *(const ushort8*)(vg2 + 8);
        }

        // S = Q K^T  (C-layout: row=quad*4+r, col=nt*16+lane15)
        f32x4 s[2][4];
        #pragma unroll
        for (int nt = 0; nt < 4; nt++) {
            bf16x8 k0 = *(const bf16x8*)&Ks[(nt * 16 + lane15) * 72 + quad * 8];
            bf16x8 k1 = *(const bf16x8*)&Ks[(nt * 16 + lane15) * 72 + 32 + quad * 8];
            #pragma unroll
            for (int mi = 0; mi < 2; mi++) {
                f32x4 z = f32x4{0.f, 0.f, 0.f, 0.f};
                z = __builtin_amdgcn_mfma_f32_16x16x32_bf16(qf[mi][0], k0, z, 0, 0, 0);
                s[mi][nt] = __builtin_amdgcn_mfma_f32_16x16x32_bf16(qf[mi][1], k1, z, 0, 0, 0);
            }
        }

        #pragma unroll
        for (int mi = 0; mi < 2; mi++) {
            if (kt * 64 + 63 > rbase + mi * 16) {   // mask needed (wave-uniform)
                #pragma unroll
                for (int nt = 0; nt < 4; nt++)
                    #pragma unroll
                    for (int r = 0; r < 4; r++) {
                        float sv = s[mi][nt][r] * SC;
                        if (kt * 64 + nt * 16 + lane15 > rbase + mi * 16 + quad * 4 + r)
                            sv = -1e9f;
                        s[mi][nt][r] = sv;
                    }
            } else {
                #pragma unroll
                for (int nt = 0; nt < 4; nt++)
                    #pragma unroll
                    for (int r = 0; r < 4; r++)
                        s[mi][nt][r] *= SC;
            }

            float mt[4];
            #pragma unroll
            for (int r = 0; r < 4; r++)
                mt[r] = fmaxf(fmaxf(s[mi][0][r], s[mi][1][r]),
                              fmaxf(s[mi][2][r], s[mi][3][r]));
            #pragma unroll
            for (int off = 1; off < 16; off <<= 1)
                #pragma unroll
                for (int r = 0; r < 4; r++)
                    mt[r] = fmaxf(mt[r], __shfl_xor(mt[r], off, 64));

            float alpha[4];
            #pragma unroll
            for (int r = 0; r < 4; r++) {
                float mn = fmaxf(mrow[mi][r], mt[r]);
                alpha[r] = exp2f(mrow[mi][r] - mn);
                mrow[mi][r] = mn;
            }
            #pragma unroll
            for (int nt = 0; nt < 4; nt++)
                #pragma unroll
                for (int r = 0; r < 4; r++)
                    s[mi][nt][r] = exp2f(s[mi][nt][r] - mrow[mi][r]);

            float rs[4];
            #pragma unroll
            for (int r = 0; r < 4; r++)
                rs[r] = (s[mi][0][r] + s[mi][1][r]) + (s[mi][2][r] + s[mi][3][r]);
            #pragma unroll
            for (int off = 1; off < 16; off <<= 1)
                #pragma unroll
                for (int r = 0; r < 4; r++)
                    rs[r] += __shfl_xor(rs[r], off, 64);
            #pragma unroll
            for (int r = 0; r < 4; r++)
                lrow[mi][r] = lrow[mi][r] * alpha[r] + rs[r];

            #pragma unroll
            for (int nt = 0; nt < 4; nt++)
                #pragma unroll
                for (int r = 0; r < 4; r++)
                    o[mi][nt][r] *= alpha[r];

            // P: C-layout -> per-wave LDS region (rows mi*16 + quad*4+r)
            #pragma unroll
            for (int nt = 0; nt < 4; nt++)
                #pragma unroll
                for (int r = 0; r < 4; r++)
                    Ps[w][(mi * 16 + quad * 4 + r) * 72 + nt * 16 + lane15] =
                        f2bf(s[mi][nt][r]);
        }

        // wave-local fence: Ps writes visible to this wave's reads; cheaper
        // than a block barrier (Ps is per-wave). Clobber blocks reordering.
        __asm__ volatile("s_waitcnt lgkmcnt(0)" ::: "memory");

        #pragma unroll
        for (int ch = 0; ch < 2; ch++) {
            bf16x8 pa0 = *(const bf16x8*)&Ps[w][(lane15) * 72 + ch * 32 + quad * 8];
            bf16x8 pa1 = *(const bf16x8*)&Ps[w][(16 + lane15) * 72 + ch * 32 + quad * 8];
            #pragma unroll
            for (int nt = 0; nt < 4; nt++) {
                bf16x8 vf = *(const bf16x8*)&Vt[(nt * 16 + lane15) * 72 + ch * 32 + quad * 8];
                o[0][nt] = __builtin_amdgcn_mfma_f32_16x16x32_bf16(pa0, vf, o[0][nt], 0, 0, 0);
                o[1][nt] = __builtin_amdgcn_mfma_f32_16x16x32_bf16(pa1, vf, o[1][nt], 0, 0, 0);
            }
        }
    }

    // write O in place over this block's Q rows (head-major layout)
    #pragma unroll
    for (int mi = 0; mi < 2; mi++)
        #pragma unroll
        for (int r = 0; r < 4; r++) {
            float inv = 1.0f / lrow[mi][r];
            size_t rb = base + (size_t)(rbase + mi * 16 + quad * 4 + r) * HD;
            #pragma unroll
            for (int nt = 0; nt < 4; nt++)
                Qb[rb + nt * 16 + lane15] = f2bf(o[mi][nt][r] * inv);
        }
}

// ---------------- launch ----------------
extern "C" void kernel_launch(void* const* d_in, const int* in_sizes, int n_in,
                              void* d_out, int out_size, void* d_ws, size_t ws_size,
                              hipStream_t stream) {
    const float* x    = (const float*)d_in[0];   // [8192][1024] fp32
    const float* wqkv = (const float*)d_in[1];   // [1024][3072] fp32
    const float* wout = (const float*)d_in[2];   // [1024][1024] fp32
    float* out = (float*)d_out;                  // [8192][1024] fp32

    // ws layout (72.5 MiB total):
    char* ws = (char*)d_ws;
    ushort_t* WqkvT = (ushort_t*)(ws);                        // [3072][1024] bf16
    ushort_t* WoutT = (ushort_t*)(ws + 6291456);              // [1024][1024] bf16
    float2*   rope  = (float2*)  (ws + 8388608);              // [2048*32]
    ushort_t* Xb    = (ushort_t*)(ws + 8912896);              // [8192][1024] bf16
    ushort_t* Qb    = (ushort_t*)(ws + 8912896 + 16777216);   // [64][2048][64]
    ushort_t* Kb    = (ushort_t*)(ws + 8912896 + 2 * 16777216);
    ushort_t* Vb    = (ushort_t*)(ws + 8912896 + 3 * 16777216);
    // VbT aliases Xb: Xb is dead after GEMM1, VbT produced after GEMM1.
    ushort_t* VbT   = Xb;                                     // [64][64][2048]

    cvt_f32_bf16<<<dim3(MM * CC / (256 * 8)), 256, 0, stream>>>(x, Xb);
    transpose_f2b<<<dim3(3 * CC / 32, CC / 32), 256, 0, stream>>>(wqkv, WqkvT, CC, 3 * CC);
    transpose_f2b<<<dim3(CC / 32, CC / 32), 256, 0, stream>>>(wout, WoutT, CC, CC);
    rope_table<<<dim3(256), 256, 0, stream>>>(rope);

    gemm_bt<1><<<dim3(3 * CC / 128, MM / 128), 256, 0, stream>>>(
        Xb, WqkvT, nullptr, Qb, Kb, Vb, rope, MM, 3 * CC, CC);

    vtrans<<<dim3(TT / 64, BB * NH), 256, 0, stream>>>(Vb, VbT);

    attn_kernel<<<dim3(TT / 128, BB * NH), 256, 0, stream>>>(Qb, Kb, VbT);

    gemm_bt<2><<<dim3(CC / 128, MM / 128), 256, 0, stream>>>(
        Qb, WoutT, out, nullptr, nullptr, nullptr, nullptr, MM, CC, CC);
}

// Round 6
// 303.872 us; speedup vs baseline: 1.5402x; 1.4328x over previous
//
#include <hip/hip_runtime.h>
#include <stdint.h>

#define DEVI __device__ __forceinline__

typedef unsigned short ushort_t;
typedef __bf16 bf16x8 __attribute__((ext_vector_type(8)));
typedef float f32x4 __attribute__((ext_vector_type(4)));
typedef unsigned short ushort8 __attribute__((ext_vector_type(8)));
typedef short s16x4 __attribute__((ext_vector_type(4)));

// ---- constants ----
#define BB 4
#define TT 2048
#define CC 1024
#define NH 16
#define HD 64
#define MM (BB*TT)          // 8192

DEVI ushort_t f2bf(float f) {
    union { float f; unsigned u; } v; v.f = f;
    return (ushort_t)((v.u + 0x7FFFu + ((v.u >> 16) & 1u)) >> 16);
}

typedef const __attribute__((address_space(1))) unsigned int guint_t;
typedef __attribute__((address_space(3))) unsigned int luint_t;

// async global->LDS, 16B/lane; lds dest is wave-uniform base + lane*16
DEVI void gl2lds16(const void* g, void* lds) {
    __builtin_amdgcn_global_load_lds((guint_t*)(uintptr_t)g,
                                     (luint_t*)(unsigned int)(uintptr_t)lds,
                                     16, 0, 0);
}

// ---------------- fp32 -> bf16 bulk convert (8 elems/thread) ----------------
__global__ void cvt_f32_bf16(const float* __restrict__ in,
                             ushort_t* __restrict__ out) {
    int i = blockIdx.x * 256 + threadIdx.x;
    const float4* p = (const float4*)in + (size_t)i * 2;
    float4 a = p[0], b = p[1];
    ushort8 r;
    r[0] = f2bf(a.x); r[1] = f2bf(a.y); r[2] = f2bf(a.z); r[3] = f2bf(a.w);
    r[4] = f2bf(b.x); r[5] = f2bf(b.y); r[6] = f2bf(b.z); r[7] = f2bf(b.w);
    *(ushort8*)(out + (size_t)i * 8) = r;
}

// ------------- transpose fp32 -> bf16: in[R][Cc] -> out[Cc][R] -------------
__global__ void transpose_f2b(const float* __restrict__ in,
                              ushort_t* __restrict__ out, int R, int Cc) {
    __shared__ ushort_t tile[32][33];
    int bx = blockIdx.x * 32;
    int by = blockIdx.y * 32;
    int tx = threadIdx.x & 31, ty = threadIdx.x >> 5;
    #pragma unroll
    for (int i = 0; i < 4; i++) {
        int r = ty * 4 + i;
        tile[r][tx] = f2bf(in[(size_t)(by + r) * Cc + bx + tx]);
    }
    __syncthreads();
    #pragma unroll
    for (int i = 0; i < 4; i++) {
        int r = ty * 4 + i;
        out[(size_t)(bx + r) * R + by + tx] = tile[tx][r];
    }
}

// ---------------- rope table: tab[t*32+j] = (cos, sin) ----------------
__global__ void rope_table(float2* __restrict__ tab) {
    int i = blockIdx.x * 256 + threadIdx.x;   // 65536 total
    int t = i >> 5, j = i & 31;
    float inv = exp2f((float)j * -0.41524101186092029f);
    float theta = (float)t * inv;
    float s, c;
    sincosf(theta, &s, &c);
    tab[i] = make_float2(c, s);
}

// ------- V transpose: Vb[bh][t][d] -> VbT[bh][d][t], 64x64 tiles -------
__global__ void vtrans(const ushort_t* __restrict__ Vb,
                       ushort_t* __restrict__ VbT) {
    __shared__ ushort_t tile[64 * 72];
    const int bh = blockIdx.y;
    const int t0 = blockIdx.x * 64;
    const int tid = threadIdx.x;
    const int r = tid >> 2, c = (tid & 3) * 16;
    const size_t base = (size_t)bh * (TT * HD);
    const ushort_t* g = Vb + base + (size_t)(t0 + r) * HD + c;
    *(ushort8*)&tile[r * 72 + c]     = *(const ushort8*)g;
    *(ushort8*)&tile[r * 72 + c + 8] = *(const ushort8*)(g + 8);
    __syncthreads();
    ushort8 a, b;
    #pragma unroll
    for (int j = 0; j < 8; j++) a[j] = tile[(c + j) * 72 + r];
    #pragma unroll
    for (int j = 0; j < 8; j++) b[j] = tile[(c + 8 + j) * 72 + r];
    ushort_t* o = VbT + base + (size_t)r * TT + t0 + c;
    *(ushort8*)o = a;
    *(ushort8*)(o + 8) = b;
}

// ---------------- GEMM: C = A * Bt^T  (A,Bt bf16), m97 structure ----------
// MODE 1: A=[M][Kd] row-major; qkv epilogue: rope q,k; scatter to [B*NH][T][HD]
// MODE 2: A head-major [(b*16+h)*2048+t][64]; fp32 store to CoutF[M][N]
template <int MODE>
__global__ __launch_bounds__(256, 2) void gemm_bt(
    const ushort_t* __restrict__ A, const ushort_t* __restrict__ Bt,
    float* __restrict__ CoutF,
    ushort_t* __restrict__ Qb, ushort_t* __restrict__ Kb, ushort_t* __restrict__ Vb,
    const float2* __restrict__ rope, int M, int N, int Kd) {
    __shared__ __attribute__((aligned(16))) ushort_t As[128 * 32];
    __shared__ __attribute__((aligned(16))) ushort_t Bs[128 * 32];

    const int tid = threadIdx.x;
    const int w = tid >> 6, l = tid & 63;
    const int lane15 = l & 15, quad = l >> 4;
    const int wm = (w >> 1) * 64, wn = (w & 1) * 64;
    const int bm = blockIdx.y, bn = blockIdx.x;

    f32x4 acc[4][4];
    #pragma unroll
    for (int i = 0; i < 4; i++)
        #pragma unroll
        for (int j = 0; j < 4; j++)
            acc[i][j] = f32x4{0.f, 0.f, 0.f, 0.f};

    const int c0 = w * 2, c1 = w * 2 + 1;
    const int lr = l >> 2, lc = (l & 3) * 8;
    const int rowA0 = bm * 128 + c0 * 16 + lr;
    const int rowA1 = bm * 128 + c1 * 16 + lr;
    const ushort_t *gA0, *gA1;
    if (MODE == 2) {
        gA0 = A + ((size_t)(rowA0 >> 11) * 32768 + (rowA0 & (TT - 1))) * HD + lc;
        gA1 = A + ((size_t)(rowA1 >> 11) * 32768 + (rowA1 & (TT - 1))) * HD + lc;
    } else {
        gA0 = A + (size_t)rowA0 * Kd + lc;
        gA1 = A + (size_t)rowA1 * Kd + lc;
    }
    const ushort_t* gB0 = Bt + (size_t)(bn * 128 + c0 * 16 + lr) * Kd + lc;
    const ushort_t* gB1 = Bt + (size_t)(bn * 128 + c1 * 16 + lr) * Kd + lc;

    for (int k0 = 0; k0 < Kd; k0 += 32) {
        size_t offA = (MODE == 2) ? ((size_t)(k0 >> 6) * 131072 + (size_t)(k0 & 63))
                                  : (size_t)k0;
        __syncthreads();   // prior iter's LDS readers done
        gl2lds16(gA0 + offA, &As[c0 * 512]);
        gl2lds16(gA1 + offA, &As[c1 * 512]);
        gl2lds16(gB0 + k0,  &Bs[c0 * 512]);
        gl2lds16(gB1 + k0,  &Bs[c1 * 512]);
        __syncthreads();   // drains vmcnt -> staged data visible

        bf16x8 af[4], bf[4];
        #pragma unroll
        for (int t = 0; t < 4; t++) {
            af[t] = *(const bf16x8*)&As[(wm + t * 16 + lane15) * 32 + quad * 8];
            bf[t] = *(const bf16x8*)&Bs[(wn + t * 16 + lane15) * 32 + quad * 8];
        }
        #pragma unroll
        for (int tm = 0; tm < 4; tm++)
            #pragma unroll
            for (int tn = 0; tn < 4; tn++)
                acc[tm][tn] = __builtin_amdgcn_mfma_f32_16x16x32_bf16(
                    af[tm], bf[tn], acc[tm][tn], 0, 0, 0);
    }

    if (MODE == 2) {
        #pragma unroll
        for (int tm = 0; tm < 4; tm++) {
            int row0 = bm * 128 + wm + tm * 16 + quad * 4;
            #pragma unroll
            for (int r = 0; r < 4; r++) {
                size_t rb = (size_t)(row0 + r) * N + bn * 128 + wn;
                #pragma unroll
                for (int tn = 0; tn < 4; tn++)
                    CoutF[rb + tn * 16 + lane15] = acc[tm][tn][r];
            }
        }
    } else {
        const int colbase = bn * 128 + wn;          // multiple of 64
        const int seg = colbase >> 10;              // 0=q 1=k 2=v
        const int h = (colbase & 1023) >> 6;        // head
        #pragma unroll
        for (int tm = 0; tm < 4; tm++) {
            int row0 = bm * 128 + wm + tm * 16 + quad * 4;
            #pragma unroll
            for (int r = 0; r < 4; r++) {
                int row = row0 + r;
                int b = row >> 11, t = row & (TT - 1);
                size_t ob = ((size_t)(b * NH + h) * TT + t) * HD;
                if (seg == 2) {
                    #pragma unroll
                    for (int tn = 0; tn < 4; tn++)
                        Vb[ob + tn * 16 + lane15] = f2bf(acc[tm][tn][r]);
                } else {
                    ushort_t* dst = (seg == 0) ? Qb : Kb;
                    #pragma unroll
                    for (int tn = 0; tn < 2; tn++) {
                        int j = tn * 16 + lane15;       // 0..31
                        float2 cs = rope[t * 32 + j];
                        float x1 = acc[tm][tn][r];      // d = j
                        float x2 = acc[tm][tn + 2][r];  // d = j+32
                        dst[ob + j]      = f2bf(x1 * cs.x - x2 * cs.y);
                        dst[ob + 32 + j] = f2bf(x2 * cs.x + x1 * cs.y);
                    }
                }
            }
        }
    }
}

// ---------------- flash attention (causal), O in place over Q --------------
// grid: (8 qt-pairs, B*NH); block 256. Block handles q-tiles {p, 15-p}:
// exactly 34 k-iterations per block -> perfect load balance.
// S^T = K*Q^T trick: S^T's C-frag (kcol=quad*4+reg, qrow=lane15) IS the
// A-operand layout of mfma_16x16x16_bf16 -> P never touches LDS.
__global__ __launch_bounds__(256, 2) void attn_kernel(
    ushort_t* __restrict__ Qb, const ushort_t* __restrict__ Kb,
    const ushort_t* __restrict__ VbT) {
    __shared__ __attribute__((aligned(16))) ushort_t Ks[64 * 72];   // K tile [t][d]
    __shared__ __attribute__((aligned(16))) ushort_t Vs[64 * 72];   // V^T tile [d][t]

    const int tid = threadIdx.x;
    const int w = tid >> 6, l = tid & 63;
    const int lane15 = l & 15, quad = l >> 4;
    const int bh = blockIdx.y;
    const size_t base = (size_t)bh * (TT * HD);
    const float SC = 0.125f * 1.4426950408889634f;  // scale * log2(e)

    const int sr = tid >> 2;         // staging row 0..63
    const int sd = (tid & 3) * 16;   // staging col 0/16/32/48
    const ushort_t* kgb = Kb  + base + (size_t)sr * HD + sd;   // + kt*64*HD
    const ushort_t* vgb = VbT + base + (size_t)sr * TT + sd;   // + kt*64

    #pragma unroll
    for (int seg = 0; seg < 2; seg++) {
        const int qt = (seg == 0) ? (int)blockIdx.x : (15 - (int)blockIdx.x);
        const int q0 = qt * 128;
        const int rbase = q0 + w * 32;
        const int ktmax = 2 * qt + 1;

        // Q fragments (B-operand of S^T: n=lane15->qrow, k=quad*8+j->dim)
        bf16x8 qf[2][2];
        #pragma unroll
        for (int mi = 0; mi < 2; mi++) {
            const ushort_t* qp = Qb + base +
                (size_t)(rbase + mi * 16 + lane15) * HD + quad * 8;
            qf[mi][0] = *(const bf16x8*)qp;
            qf[mi][1] = *(const bf16x8*)(qp + 32);
        }

        f32x4 o[2][4];
        #pragma unroll
        for (int mi = 0; mi < 2; mi++)
            #pragma unroll
            for (int nt = 0; nt < 4; nt++) o[mi][nt] = f32x4{0.f, 0.f, 0.f, 0.f};
        float mrow[2] = {-INFINITY, -INFINITY};   // per qrow=lane15
        float lrow[2] = {0.f, 0.f};

        // prefetch tile 0 of this segment
        const ushort_t* kg = kgb;
        const ushort_t* vg = vgb;
        ushort8 kr0 = *(const ushort8*)kg, kr1 = *(const ushort8*)(kg + 8);
        ushort8 vr0 = *(const ushort8*)vg, vr1 = *(const ushort8*)(vg + 8);

        for (int kt = 0; kt <= ktmax; kt++) {
            __syncthreads();   // prior iter's LDS readers done
            *(ushort8*)&Ks[sr * 72 + sd]     = kr0;
            *(ushort8*)&Ks[sr * 72 + sd + 8] = kr1;
            *(ushort8*)&Vs[sr * 72 + sd]     = vr0;
            *(ushort8*)&Vs[sr * 72 + sd + 8] = vr1;
            __syncthreads();
            if (kt < ktmax) {   // prefetch next tile; overlaps compute
                const ushort_t* kg2 = kgb + (size_t)(kt + 1) * 64 * HD;
                const ushort_t* vg2 = vgb + (size_t)(kt + 1) * 64;
                kr0 = *(const ushort8*)kg2; kr1 = *(const ushort8*)(kg2 + 8);
                vr0 = *(const ushort8*)vg2; vr1 = *(const ushort8*)(vg2 + 8);
            }

            // K A-frags (shared across mi): m=lane15->kcol, k=quad*8+j->dim
            bf16x8 ka[4][2];
            #pragma unroll
            for (int c = 0; c < 4; c++) {
                ka[c][0] = *(const bf16x8*)&Ks[(c * 16 + lane15) * 72 + quad * 8];
                ka[c][1] = *(const bf16x8*)&Ks[(c * 16 + lane15) * 72 + 32 + quad * 8];
            }
            // V B-frags: n=lane15->d, k=quad*4+j->kcol (from V^T tile)
            s16x4 vf[4][4];
            #pragma unroll
            for (int c = 0; c < 4; c++)
                #pragma unroll
                for (int nt = 0; nt < 4; nt++)
                    vf[c][nt] = *(const s16x4*)&Vs[(nt * 16 + lane15) * 72 +
                                                   c * 16 + quad * 4];

            #pragma unroll
            for (int mi = 0; mi < 2; mi++) {
                // S^T tiles: D[kcol][qrow], kcol=c*16+quad*4+reg, qrow=lane15
                f32x4 s[4];
                #pragma unroll
                for (int c = 0; c < 4; c++) {
                    f32x4 z = f32x4{0.f, 0.f, 0.f, 0.f};
                    z = __builtin_amdgcn_mfma_f32_16x16x32_bf16(ka[c][0], qf[mi][0], z, 0, 0, 0);
                    s[c] = __builtin_amdgcn_mfma_f32_16x16x32_bf16(ka[c][1], qf[mi][1], z, 0, 0, 0);
                }

                const int qrow = rbase + mi * 16 + lane15;
                if (kt * 64 + 63 > rbase + mi * 16) {   // masking needed
                    #pragma unroll
                    for (int c = 0; c < 4; c++)
                        #pragma unroll
                        for (int r = 0; r < 4; r++) {
                            float sv = s[c][r] * SC;
                            if (kt * 64 + c * 16 + quad * 4 + r > qrow) sv = -1e9f;
                            s[c][r] = sv;
                        }
                } else {
                    #pragma unroll
                    for (int c = 0; c < 4; c++)
                        #pragma unroll
                        for (int r = 0; r < 4; r++) s[c][r] *= SC;
                }

                // per-qrow max: 16 in-lane + quad reduction (2 shuffles)
                float mt = s[0][0];
                #pragma unroll
                for (int c = 0; c < 4; c++)
                    #pragma unroll
                    for (int r = 0; r < 4; r++) mt = fmaxf(mt, s[c][r]);
                mt = fmaxf(mt, __shfl_xor(mt, 16, 64));
                mt = fmaxf(mt, __shfl_xor(mt, 32, 64));

                float mn = fmaxf(mrow[mi], mt);
                float alpha = exp2f(mrow[mi] - mn);
                mrow[mi] = mn;

                #pragma unroll
                for (int c = 0; c < 4; c++)
                    #pragma unroll
                    for (int r = 0; r < 4; r++)
                        s[c][r] = exp2f(s[c][r] - mn);

                float rs = 0.f;
                #pragma unroll
                for (int c = 0; c < 4; c++)
                    rs += (s[c][0] + s[c][1]) + (s[c][2] + s[c][3]);
                rs += __shfl_xor(rs, 16, 64);
                rs += __shfl_xor(rs, 32, 64);
                lrow[mi] = lrow[mi] * alpha + rs;

                // alpha lives in lane=qrow (0..15); o rows are quad*4+r
                #pragma unroll
                for (int r = 0; r < 4; r++) {
                    float aO = __shfl(alpha, quad * 4 + r, 64);
                    #pragma unroll
                    for (int nt = 0; nt < 4; nt++) o[mi][nt][r] *= aO;
                }

                // P A-frags: m=lane15->qrow, k=quad*4+j->kcol == S^T C-frag
                s16x4 pf[4];
                #pragma unroll
                for (int c = 0; c < 4; c++)
                    #pragma unroll
                    for (int r = 0; r < 4; r++)
                        pf[c][r] = (short)f2bf(s[c][r]);

                #pragma unroll
                for (int c = 0; c < 4; c++)
                    #pragma unroll
                    for (int nt = 0; nt < 4; nt++)
                        o[mi][nt] = __builtin_amdgcn_mfma_f32_16x16x16bf16_1k(
                            pf[c], vf[c][nt], o[mi][nt], 0, 0, 0);
            }
        }

        // epilogue: O in place over this segment's Q rows (head-major)
        #pragma unroll
        for (int mi = 0; mi < 2; mi++) {
            float linv = 1.0f / lrow[mi];   // lane=qrow domain
            #pragma unroll
            for (int r = 0; r < 4; r++) {
                float lO = __shfl(linv, quad * 4 + r, 64);
                size_t rb = base + (size_t)(rbase + mi * 16 + quad * 4 + r) * HD;
                #pragma unroll
                for (int nt = 0; nt < 4; nt++)
                    Qb[rb + nt * 16 + lane15] = f2bf(o[mi][nt][r] * lO);
            }
        }
        __syncthreads();   // segment boundary: LDS reuse
    }
}

// ---------------- launch ----------------
extern "C" void kernel_launch(void* const* d_in, const int* in_sizes, int n_in,
                              void* d_out, int out_size, void* d_ws, size_t ws_size,
                              hipStream_t stream) {
    const float* x    = (const float*)d_in[0];   // [8192][1024] fp32
    const float* wqkv = (const float*)d_in[1];   // [1024][3072] fp32
    const float* wout = (const float*)d_in[2];   // [1024][1024] fp32
    float* out = (float*)d_out;                  // [8192][1024] fp32

    // ws layout (72.5 MiB total):
    char* ws = (char*)d_ws;
    ushort_t* WqkvT = (ushort_t*)(ws);                        // [3072][1024] bf16
    ushort_t* WoutT = (ushort_t*)(ws + 6291456);              // [1024][1024] bf16
    float2*   rope  = (float2*)  (ws + 8388608);              // [2048*32]
    ushort_t* Xb    = (ushort_t*)(ws + 8912896);              // [8192][1024] bf16
    ushort_t* Qb    = (ushort_t*)(ws + 8912896 + 16777216);   // [64][2048][64]
    ushort_t* Kb    = (ushort_t*)(ws + 8912896 + 2 * 16777216);
    ushort_t* Vb    = (ushort_t*)(ws + 8912896 + 3 * 16777216);
    // VbT aliases Xb: Xb is dead after GEMM1, VbT produced after GEMM1.
    ushort_t* VbT   = Xb;                                     // [64][64][2048]

    cvt_f32_bf16<<<dim3(MM * CC / (256 * 8)), 256, 0, stream>>>(x, Xb);
    transpose_f2b<<<dim3(3 * CC / 32, CC / 32), 256, 0, stream>>>(wqkv, WqkvT, CC, 3 * CC);
    transpose_f2b<<<dim3(CC / 32, CC / 32), 256, 0, stream>>>(wout, WoutT, CC, CC);
    rope_table<<<dim3(256), 256, 0, stream>>>(rope);

    gemm_bt<1><<<dim3(3 * CC / 128, MM / 128), 256, 0, stream>>>(
        Xb, WqkvT, nullptr, Qb, Kb, Vb, rope, MM, 3 * CC, CC);

    vtrans<<<dim3(TT / 64, BB * NH), 256, 0, stream>>>(Vb, VbT);

    attn_kernel<<<dim3(8, BB * NH), 256, 0, stream>>>(Qb, Kb, VbT);

    gemm_bt<2><<<dim3(CC / 128, MM / 128), 256, 0, stream>>>(
        Qb, WoutT, out, nullptr, nullptr, nullptr, nullptr, MM, CC, CC);
}

// Round 7
// 279.298 us; speedup vs baseline: 1.6757x; 1.0880x over previous
//
#include <hip/hip_runtime.h>
#include <stdint.h>

#define DEVI __device__ __forceinline__

typedef unsigned short ushort_t;
typedef __bf16 bf16x8 __attribute__((ext_vector_type(8)));
typedef float f32x4 __attribute__((ext_vector_type(4)));
typedef unsigned short ushort8 __attribute__((ext_vector_type(8)));
typedef short s16x4 __attribute__((ext_vector_type(4)));

// ---- constants ----
#define BB 4
#define TT 2048
#define CC 1024
#define NH 16
#define HD 64
#define MM (BB*TT)          // 8192

DEVI ushort_t f2bf(float f) {
    union { float f; unsigned u; } v; v.f = f;
    return (ushort_t)((v.u + 0x7FFFu + ((v.u >> 16) & 1u)) >> 16);
}

typedef const __attribute__((address_space(1))) unsigned int guint_t;
typedef __attribute__((address_space(3))) unsigned int luint_t;

// async global->LDS, 16B/lane; lds dest is wave-uniform base + lane*16
DEVI void gl2lds16(const void* g, void* lds) {
    __builtin_amdgcn_global_load_lds((guint_t*)(uintptr_t)g,
                                     (luint_t*)(unsigned int)(uintptr_t)lds,
                                     16, 0, 0);
}

// ---------------- fp32 -> bf16 bulk convert (8 elems/thread) ----------------
__global__ void cvt_f32_bf16(const float* __restrict__ in,
                             ushort_t* __restrict__ out) {
    int i = blockIdx.x * 256 + threadIdx.x;
    const float4* p = (const float4*)in + (size_t)i * 2;
    float4 a = p[0], b = p[1];
    ushort8 r;
    r[0] = f2bf(a.x); r[1] = f2bf(a.y); r[2] = f2bf(a.z); r[3] = f2bf(a.w);
    r[4] = f2bf(b.x); r[5] = f2bf(b.y); r[6] = f2bf(b.z); r[7] = f2bf(b.w);
    *(ushort8*)(out + (size_t)i * 8) = r;
}

// ------------- transpose fp32 -> bf16: in[R][Cc] -> out[Cc][R] -------------
__global__ void transpose_f2b(const float* __restrict__ in,
                              ushort_t* __restrict__ out, int R, int Cc) {
    __shared__ ushort_t tile[32][33];
    int bx = blockIdx.x * 32;
    int by = blockIdx.y * 32;
    int tx = threadIdx.x & 31, ty = threadIdx.x >> 5;
    #pragma unroll
    for (int i = 0; i < 4; i++) {
        int r = ty * 4 + i;
        tile[r][tx] = f2bf(in[(size_t)(by + r) * Cc + bx + tx]);
    }
    __syncthreads();
    #pragma unroll
    for (int i = 0; i < 4; i++) {
        int r = ty * 4 + i;
        out[(size_t)(bx + r) * R + by + tx] = tile[tx][r];
    }
}

// ---------------- rope table: tab[t*32+j] = (cos, sin) ----------------
__global__ void rope_table(float2* __restrict__ tab) {
    int i = blockIdx.x * 256 + threadIdx.x;   // 65536 total
    int t = i >> 5, j = i & 31;
    float inv = exp2f((float)j * -0.41524101186092029f);
    float theta = (float)t * inv;
    float s, c;
    sincosf(theta, &s, &c);
    tab[i] = make_float2(c, s);
}

// ------- V transpose: Vb[bh][t][d] -> VbT[bh][d][t], 64x64 tiles -------
__global__ void vtrans(const ushort_t* __restrict__ Vb,
                       ushort_t* __restrict__ VbT) {
    __shared__ ushort_t tile[64 * 72];
    const int bh = blockIdx.y;
    const int t0 = blockIdx.x * 64;
    const int tid = threadIdx.x;
    const int r = tid >> 2, c = (tid & 3) * 16;
    const size_t base = (size_t)bh * (TT * HD);
    const ushort_t* g = Vb + base + (size_t)(t0 + r) * HD + c;
    *(ushort8*)&tile[r * 72 + c]     = *(const ushort8*)g;
    *(ushort8*)&tile[r * 72 + c + 8] = *(const ushort8*)(g + 8);
    __syncthreads();
    ushort8 a, b;
    #pragma unroll
    for (int j = 0; j < 8; j++) a[j] = tile[(c + j) * 72 + r];
    #pragma unroll
    for (int j = 0; j < 8; j++) b[j] = tile[(c + 8 + j) * 72 + r];
    ushort_t* o = VbT + base + (size_t)r * TT + t0 + c;
    *(ushort8*)o = a;
    *(ushort8*)(o + 8) = b;
}

// ---------------- GEMM: C = A * Bt^T  (A,Bt bf16), m97 structure ----------
// MODE 1: A=[M][Kd] row-major; qkv epilogue: rope q,k (q pre-scaled by
//         scale*log2e so attention needs no score multiply); scatter to
//         [B*NH][T][HD]
// MODE 2: A head-major [(b*16+h)*2048+t][64]; fp32 store to CoutF[M][N]
template <int MODE>
__global__ __launch_bounds__(256, 2) void gemm_bt(
    const ushort_t* __restrict__ A, const ushort_t* __restrict__ Bt,
    float* __restrict__ CoutF,
    ushort_t* __restrict__ Qb, ushort_t* __restrict__ Kb, ushort_t* __restrict__ Vb,
    const float2* __restrict__ rope, int M, int N, int Kd) {
    __shared__ __attribute__((aligned(16))) ushort_t As[128 * 32];
    __shared__ __attribute__((aligned(16))) ushort_t Bs[128 * 32];

    const int tid = threadIdx.x;
    const int w = tid >> 6, l = tid & 63;
    const int lane15 = l & 15, quad = l >> 4;
    const int wm = (w >> 1) * 64, wn = (w & 1) * 64;
    const int bm = blockIdx.y, bn = blockIdx.x;

    f32x4 acc[4][4];
    #pragma unroll
    for (int i = 0; i < 4; i++)
        #pragma unroll
        for (int j = 0; j < 4; j++)
            acc[i][j] = f32x4{0.f, 0.f, 0.f, 0.f};

    const int c0 = w * 2, c1 = w * 2 + 1;
    const int lr = l >> 2, lc = (l & 3) * 8;
    const int rowA0 = bm * 128 + c0 * 16 + lr;
    const int rowA1 = bm * 128 + c1 * 16 + lr;
    const ushort_t *gA0, *gA1;
    if (MODE == 2) {
        gA0 = A + ((size_t)(rowA0 >> 11) * 32768 + (rowA0 & (TT - 1))) * HD + lc;
        gA1 = A + ((size_t)(rowA1 >> 11) * 32768 + (rowA1 & (TT - 1))) * HD + lc;
    } else {
        gA0 = A + (size_t)rowA0 * Kd + lc;
        gA1 = A + (size_t)rowA1 * Kd + lc;
    }
    const ushort_t* gB0 = Bt + (size_t)(bn * 128 + c0 * 16 + lr) * Kd + lc;
    const ushort_t* gB1 = Bt + (size_t)(bn * 128 + c1 * 16 + lr) * Kd + lc;

    for (int k0 = 0; k0 < Kd; k0 += 32) {
        size_t offA = (MODE == 2) ? ((size_t)(k0 >> 6) * 131072 + (size_t)(k0 & 63))
                                  : (size_t)k0;
        __syncthreads();   // prior iter's LDS readers done
        gl2lds16(gA0 + offA, &As[c0 * 512]);
        gl2lds16(gA1 + offA, &As[c1 * 512]);
        gl2lds16(gB0 + k0,  &Bs[c0 * 512]);
        gl2lds16(gB1 + k0,  &Bs[c1 * 512]);
        __syncthreads();   // drains vmcnt -> staged data visible

        bf16x8 af[4], bf[4];
        #pragma unroll
        for (int t = 0; t < 4; t++) {
            af[t] = *(const bf16x8*)&As[(wm + t * 16 + lane15) * 32 + quad * 8];
            bf[t] = *(const bf16x8*)&Bs[(wn + t * 16 + lane15) * 32 + quad * 8];
        }
        #pragma unroll
        for (int tm = 0; tm < 4; tm++)
            #pragma unroll
            for (int tn = 0; tn < 4; tn++)
                acc[tm][tn] = __builtin_amdgcn_mfma_f32_16x16x32_bf16(
                    af[tm], bf[tn], acc[tm][tn], 0, 0, 0);
    }

    if (MODE == 2) {
        #pragma unroll
        for (int tm = 0; tm < 4; tm++) {
            int row0 = bm * 128 + wm + tm * 16 + quad * 4;
            #pragma unroll
            for (int r = 0; r < 4; r++) {
                size_t rb = (size_t)(row0 + r) * N + bn * 128 + wn;
                #pragma unroll
                for (int tn = 0; tn < 4; tn++)
                    CoutF[rb + tn * 16 + lane15] = acc[tm][tn][r];
            }
        }
    } else {
        const float SCQ = 0.125f * 1.4426950408889634f;   // folded into Q
        const int colbase = bn * 128 + wn;          // multiple of 64
        const int seg = colbase >> 10;              // 0=q 1=k 2=v
        const int h = (colbase & 1023) >> 6;        // head
        #pragma unroll
        for (int tm = 0; tm < 4; tm++) {
            int row0 = bm * 128 + wm + tm * 16 + quad * 4;
            #pragma unroll
            for (int r = 0; r < 4; r++) {
                int row = row0 + r;
                int b = row >> 11, t = row & (TT - 1);
                size_t ob = ((size_t)(b * NH + h) * TT + t) * HD;
                if (seg == 2) {
                    #pragma unroll
                    for (int tn = 0; tn < 4; tn++)
                        Vb[ob + tn * 16 + lane15] = f2bf(acc[tm][tn][r]);
                } else {
                    ushort_t* dst = (seg == 0) ? Qb : Kb;
                    #pragma unroll
                    for (int tn = 0; tn < 2; tn++) {
                        int j = tn * 16 + lane15;       // 0..31
                        float2 cs = rope[t * 32 + j];
                        float x1 = acc[tm][tn][r];      // d = j
                        float x2 = acc[tm][tn + 2][r];  // d = j+32
                        float y1 = x1 * cs.x - x2 * cs.y;
                        float y2 = x2 * cs.x + x1 * cs.y;
                        if (seg == 0) { y1 *= SCQ; y2 *= SCQ; }
                        dst[ob + j]      = f2bf(y1);
                        dst[ob + 32 + j] = f2bf(y2);
                    }
                }
            }
        }
    }
}

// ---------------- flash attention (causal), O in place over Q --------------
// grid: (8 qt-pairs, B*NH); block 512 = 8 waves x 16 q-rows. Block handles
// q-tiles {p, 15-p} of 128 rows: exactly 34 k-iterations -> perfect balance.
// S^T = K*Q^T: S^T's C-frag (kcol=quad*4+reg, qrow=lane15) IS the A-operand
// layout of mfma_16x16x16_bf16 -> P never touches LDS. Q pre-scaled by
// scale*log2e in GEMM1, so scores are already in the exp2 domain.
__global__ __launch_bounds__(512, 4) void attn_kernel(
    ushort_t* __restrict__ Qb, const ushort_t* __restrict__ Kb,
    const ushort_t* __restrict__ VbT) {
    __shared__ __attribute__((aligned(16))) ushort_t Ks[64 * 72];   // K tile [t][d]
    __shared__ __attribute__((aligned(16))) ushort_t Vs[64 * 72];   // V^T tile [d][t]

    const int tid = threadIdx.x;
    const int w = tid >> 6, l = tid & 63;
    const int lane15 = l & 15, quad = l >> 4;
    const int bh = blockIdx.y;
    const size_t base = (size_t)bh * (TT * HD);

    const int sr = tid >> 3;         // staging row 0..63
    const int sd = (tid & 7) * 8;    // staging col (elems), 16B per thread
    const ushort_t* kgb = Kb  + base + (size_t)sr * HD + sd;   // + kt*64*HD
    const ushort_t* vgb = VbT + base + (size_t)sr * TT + sd;   // + kt*64

    #pragma unroll
    for (int seg = 0; seg < 2; seg++) {
        const int qt = (seg == 0) ? (int)blockIdx.x : (15 - (int)blockIdx.x);
        const int q0 = qt * 128;
        const int rbase = q0 + w * 16;     // wave owns 16 q-rows
        const int ktmax = 2 * qt + 1;

        // Q fragments (B-operand of S^T: n=lane15->qrow, k=quad*8+j->dim)
        bf16x8 qf0, qf1;
        {
            const ushort_t* qp = Qb + base + (size_t)(rbase + lane15) * HD + quad * 8;
            qf0 = *(const bf16x8*)qp;
            qf1 = *(const bf16x8*)(qp + 32);
        }

        f32x4 o[4];
        #pragma unroll
        for (int nt = 0; nt < 4; nt++) o[nt] = f32x4{0.f, 0.f, 0.f, 0.f};
        float mrow = -INFINITY, lrow = 0.f;   // per qrow=lane15

        // prefetch tile 0 of this segment
        ushort8 kr = *(const ushort8*)kgb;
        ushort8 vr = *(const ushort8*)vgb;

        for (int kt = 0; kt <= ktmax; kt++) {
            __syncthreads();   // prior iter's LDS readers done
            *(ushort8*)&Ks[sr * 72 + sd] = kr;
            *(ushort8*)&Vs[sr * 72 + sd] = vr;
            __syncthreads();
            if (kt < ktmax) {   // prefetch next tile; overlaps compute
                kr = *(const ushort8*)(kgb + (size_t)(kt + 1) * 64 * HD);
                vr = *(const ushort8*)(vgb + (size_t)(kt + 1) * 64);
            }

            // S^T tiles: D[kcol][qrow], kcol=c*16+quad*4+reg, qrow=lane15
            f32x4 s[4];
            #pragma unroll
            for (int c = 0; c < 4; c++) {
                bf16x8 k0 = *(const bf16x8*)&Ks[(c * 16 + lane15) * 72 + quad * 8];
                bf16x8 k1 = *(const bf16x8*)&Ks[(c * 16 + lane15) * 72 + 32 + quad * 8];
                f32x4 z = f32x4{0.f, 0.f, 0.f, 0.f};
                z = __builtin_amdgcn_mfma_f32_16x16x32_bf16(k0, qf0, z, 0, 0, 0);
                s[c] = __builtin_amdgcn_mfma_f32_16x16x32_bf16(k1, qf1, z, 0, 0, 0);
            }

            const int qrow = rbase + lane15;
            if (kt * 64 + 63 > rbase) {   // masking needed (wave-uniform)
                #pragma unroll
                for (int c = 0; c < 4; c++)
                    #pragma unroll
                    for (int r = 0; r < 4; r++)
                        if (kt * 64 + c * 16 + quad * 4 + r > qrow) s[c][r] = -1e9f;
            }

            // per-qrow max: 16 in-lane + cross-quad (2 shuffles)
            float mt = s[0][0];
            #pragma unroll
            for (int c = 0; c < 4; c++)
                #pragma unroll
                for (int r = 0; r < 4; r++) mt = fmaxf(mt, s[c][r]);
            mt = fmaxf(mt, __shfl_xor(mt, 16, 64));
            mt = fmaxf(mt, __shfl_xor(mt, 32, 64));

            float mn = fmaxf(mrow, mt);
            float alpha = __builtin_amdgcn_exp2f(mrow - mn);
            mrow = mn;

            #pragma unroll
            for (int c = 0; c < 4; c++)
                #pragma unroll
                for (int r = 0; r < 4; r++)
                    s[c][r] = __builtin_amdgcn_exp2f(s[c][r] - mn);

            float rs = 0.f;
            #pragma unroll
            for (int c = 0; c < 4; c++)
                rs += (s[c][0] + s[c][1]) + (s[c][2] + s[c][3]);
            rs += __shfl_xor(rs, 16, 64);
            rs += __shfl_xor(rs, 32, 64);
            lrow = lrow * alpha + rs;

            // alpha lives in lane=qrow (replicated across quads); o rows are
            // qrow = rbase + quad*4 + r -> broadcast from lane quad*4+r
            #pragma unroll
            for (int r = 0; r < 4; r++) {
                float aO = __shfl(alpha, quad * 4 + r, 64);
                #pragma unroll
                for (int nt = 0; nt < 4; nt++) o[nt][r] *= aO;
            }

            // P A-frags (m=lane15->qrow, k=quad*4+j->kcol) == S^T C-frag
            #pragma unroll
            for (int c = 0; c < 4; c++) {
                s16x4 pf;
                #pragma unroll
                for (int r = 0; r < 4; r++) pf[r] = (short)f2bf(s[c][r]);
                #pragma unroll
                for (int nt = 0; nt < 4; nt++) {
                    s16x4 vf = *(const s16x4*)&Vs[(nt * 16 + lane15) * 72 +
                                                  c * 16 + quad * 4];
                    o[nt] = __builtin_amdgcn_mfma_f32_16x16x16bf16_1k(
                        pf, vf, o[nt], 0, 0, 0);
                }
            }
        }

        // epilogue: O in place over this wave's Q rows (head-major)
        float linv = 1.0f / lrow;   // lane=qrow domain
        #pragma unroll
        for (int r = 0; r < 4; r++) {
            float lO = __shfl(linv, quad * 4 + r, 64);
            size_t rb = base + (size_t)(rbase + quad * 4 + r) * HD;
            #pragma unroll
            for (int nt = 0; nt < 4; nt++)
                Qb[rb + nt * 16 + lane15] = f2bf(o[nt][r] * lO);
        }
    }
}

// ---------------- launch ----------------
extern "C" void kernel_launch(void* const* d_in, const int* in_sizes, int n_in,
                              void* d_out, int out_size, void* d_ws, size_t ws_size,
                              hipStream_t stream) {
    const float* x    = (const float*)d_in[0];   // [8192][1024] fp32
    const float* wqkv = (const float*)d_in[1];   // [1024][3072] fp32
    const float* wout = (const float*)d_in[2];   // [1024][1024] fp32
    float* out = (float*)d_out;                  // [8192][1024] fp32

    // ws layout (72.5 MiB total):
    char* ws = (char*)d_ws;
    ushort_t* WqkvT = (ushort_t*)(ws);                        // [3072][1024] bf16
    ushort_t* WoutT = (ushort_t*)(ws + 6291456);              // [1024][1024] bf16
    float2*   rope  = (float2*)  (ws + 8388608);              // [2048*32]
    ushort_t* Xb    = (ushort_t*)(ws + 8912896);              // [8192][1024] bf16
    ushort_t* Qb    = (ushort_t*)(ws + 8912896 + 16777216);   // [64][2048][64]
    ushort_t* Kb    = (ushort_t*)(ws + 8912896 + 2 * 16777216);
    ushort_t* Vb    = (ushort_t*)(ws + 8912896 + 3 * 16777216);
    // VbT aliases Xb: Xb is dead after GEMM1, VbT produced after GEMM1.
    ushort_t* VbT   = Xb;                                     // [64][64][2048]

    cvt_f32_bf16<<<dim3(MM * CC / (256 * 8)), 256, 0, stream>>>(x, Xb);
    transpose_f2b<<<dim3(3 * CC / 32, CC / 32), 256, 0, stream>>>(wqkv, WqkvT, CC, 3 * CC);
    transpose_f2b<<<dim3(CC / 32, CC / 32), 256, 0, stream>>>(wout, WoutT, CC, CC);
    rope_table<<<dim3(256), 256, 0, stream>>>(rope);

    gemm_bt<1><<<dim3(3 * CC / 128, MM / 128), 256, 0, stream>>>(
        Xb, WqkvT, nullptr, Qb, Kb, Vb, rope, MM, 3 * CC, CC);

    vtrans<<<dim3(TT / 64, BB * NH), 256, 0, stream>>>(Vb, VbT);

    attn_kernel<<<dim3(8, BB * NH), 512, 0, stream>>>(Qb, Kb, VbT);

    gemm_bt<2><<<dim3(CC / 128, MM / 128), 256, 0, stream>>>(
        Qb, WoutT, out, nullptr, nullptr, nullptr, nullptr, MM, CC, CC);
}